// Round 7
// baseline (273.081 us; speedup 1.0000x reference)
//
#include <hip/hip_runtime.h>
#include <hip/hip_bf16.h>

#define B_ 4
#define N_ 4096
#define D_ 128
#define KSEG 4
#define QSEG 4
#define NSEG (N_ / KSEG)   // 1024 keys per attn wave
#define QSEGN (N_ / QSEG)  // 1024 q's per stats wave

typedef __bf16 bf16x8 __attribute__((ext_vector_type(8)));
typedef __bf16 bf16x4 __attribute__((ext_vector_type(4)));
typedef float f32x4 __attribute__((ext_vector_type(4)));

// alpha = log2(e) / sqrt(128), folded into Qb at conversion time
#define ALPHA 0.12752361680972262f

// ws layout:
//   Qb   : bf16 [B][N][D]        @ 0       (alpha-prescaled)
//   Kb   : bf16 [B][N][D]        @ 4 MiB
//   Vt   : bf16 [B][D][N]        @ 8 MiB   (transposed V; linv-scaled in place)
//   l    : f32  [B][N]           @ 12 MiB
//   linv : f32  [B][N]           @ 12 MiB + 64 KiB
//   part : f32  [KSEG][B][N][D]  @ 13 MiB  (32 MiB)
#define OFF_KB   (4u << 20)
#define OFF_VT   (8u << 20)
#define OFF_L    (12u << 20)
#define OFF_LINV ((12u << 20) + (64u << 10))
#define OFF_PART (13u << 20)

// ---------------------------------------------------------------------------
// Kernel A: convert Q*alpha,K -> bf16; convert+transpose V -> Vt
// ---------------------------------------------------------------------------
__global__ __launch_bounds__(256) void cvt_kernel(
    const float* __restrict__ q, const float* __restrict__ k,
    const float* __restrict__ v,
    __bf16* __restrict__ qb, __bf16* __restrict__ kb, __bf16* __restrict__ vt)
{
    int bid = blockIdx.x;
    int tid = threadIdx.x;
    if (bid < 4096) {
        int i4 = bid * 256 + tid;
        const float4* src;
        __bf16* dst;
        int off;
        float sc;
        if (i4 < (B_ * N_ * D_ / 4)) { src = (const float4*)q; dst = qb; off = i4; sc = ALPHA; }
        else { src = (const float4*)k; dst = kb; off = i4 - B_ * N_ * D_ / 4; sc = 1.f; }
        float4 x = src[off];
        bf16x4 y;
        y[0] = (__bf16)(x.x * sc); y[1] = (__bf16)(x.y * sc);
        y[2] = (__bf16)(x.z * sc); y[3] = (__bf16)(x.w * sc);
        *(bf16x4*)(dst + (size_t)off * 4) = y;
    } else {
        int g = (bid - 4096) * 256 + tid;
        int kg = g & 1023;
        int rest = g >> 10;
        int d = rest & 127;
        int b = rest >> 7;
        const float* vp = v + ((size_t)b * N_ + (size_t)kg * 4) * D_ + d;
        bf16x4 y;
        y[0] = (__bf16)vp[0];
        y[1] = (__bf16)vp[D_];
        y[2] = (__bf16)vp[2 * D_];
        y[3] = (__bf16)vp[3 * D_];
        *(bf16x4*)(vt + ((size_t)b * D_ + d) * N_ + (size_t)kg * 4) = y;
    }
}

// ---------------------------------------------------------------------------
// Kernel B: column stats — BARRIER-FREE. Each wave independently owns 32 keys
// (A-frags resident) and loops 16-q steps, Q B-frags loaded directly from
// global (lane l15 = q row -> contiguous bf16x8), next step's frags
// register-prefetched. No LDS, no __syncthreads.
// grid = B * (N/128) * QSEG = 512 blocks of 256 (4 independent waves).
// ---------------------------------------------------------------------------
__global__ __launch_bounds__(256, 4) void stats_kernel(
    const __bf16* __restrict__ qb, const __bf16* __restrict__ kb,
    float* __restrict__ l)
{
    int idx = blockIdx.x;
    int qseg = idx & (QSEG - 1);
    int ktile = (idx >> 2) & 31;           // 32 tiles of 128 keys
    int b = idx >> 7;
    int w = threadIdx.x >> 6;
    int L = threadIdx.x & 63;
    int quad = L >> 4, l15 = L & 15;

    const bf16x8* kv = (const bf16x8*)(kb + (size_t)b * N_ * D_);
    const bf16x8* qv = (const bf16x8*)(qb + (size_t)b * N_ * D_);

    int key_base = ktile * 128 + w * 32;   // this wave's 32 keys
    bf16x8 af[2][4];
#pragma unroll
    for (int i = 0; i < 2; ++i)
#pragma unroll
        for (int f = 0; f < 4; ++f)
            af[i][f] = kv[(key_base + i * 16 + l15) * 16 + f * 4 + quad];

    int q0 = qseg * QSEGN;
    bf16x8 qc[4], qn[4];
#pragma unroll
    for (int f = 0; f < 4; ++f)
        qc[f] = qv[(q0 + l15) * 16 + f * 4 + quad];

    float ps[8];
#pragma unroll
    for (int s = 0; s < 8; ++s) ps[s] = 0.f;

    const int T = QSEGN / 16;              // 64
    for (int t = 0; t < T; ++t) {
        int tn = (t + 1 < T) ? t + 1 : t;
#pragma unroll
        for (int f = 0; f < 4; ++f)
            qn[f] = qv[(q0 + tn * 16 + l15) * 16 + f * 4 + quad];
#pragma unroll
        for (int i = 0; i < 2; ++i) {
            f32x4 acc = {0.f, 0.f, 0.f, 0.f};
#pragma unroll
            for (int f = 0; f < 4; ++f)
                acc = __builtin_amdgcn_mfma_f32_16x16x32_bf16(af[i][f], qc[f], acc, 0, 0, 0);
#pragma unroll
            for (int r = 0; r < 4; ++r)
                ps[i * 4 + r] += __builtin_amdgcn_exp2f(acc[r]);
        }
#pragma unroll
        for (int f = 0; f < 4; ++f) qc[f] = qn[f];
    }
    // reduce over the 16 q-columns (lanes sharing a quad)
#pragma unroll
    for (int m = 1; m <= 8; m <<= 1)
#pragma unroll
        for (int s = 0; s < 8; ++s)
            ps[s] += __shfl_xor(ps[s], m, 64);
    if (l15 == 0) {
        // key = key_base + i*16 + quad*4 + r
        float* dst = l + (size_t)b * N_ + key_base + quad * 4;
#pragma unroll
        for (int i = 0; i < 2; ++i)
#pragma unroll
            for (int r = 0; r < 4; ++r)
                atomicAdd(dst + i * 16 + r, ps[i * 4 + r]);
    }
}

// ---------------------------------------------------------------------------
// Kernel C: linv = 1/l
// ---------------------------------------------------------------------------
__global__ __launch_bounds__(256) void recip_kernel(
    const float* __restrict__ l, float* __restrict__ linv)
{
    int i = blockIdx.x * 256 + threadIdx.x;
    linv[i] = 1.f / l[i];
}

// ---------------------------------------------------------------------------
// Kernel C2: Vt[b][d][k] *= linv[b][k]
// ---------------------------------------------------------------------------
__global__ __launch_bounds__(256) void scalev_kernel(
    const float* __restrict__ linv, __bf16* __restrict__ vt)
{
    int i = blockIdx.x * 256 + threadIdx.x;  // bf16x8 chunk index
    int row = i >> 9;                        // (b,d) row; N_/8 = 512 chunks/row
    int b = row >> 7;
    int k0 = (i & 511) * 8;
    const float* lp = linv + (size_t)b * N_ + k0;
    float4 a = *(const float4*)lp;
    float4 c = *(const float4*)(lp + 4);
    bf16x8 v = ((const bf16x8*)vt)[i];
    bf16x8 o;
    o[0] = (__bf16)((float)v[0] * a.x); o[1] = (__bf16)((float)v[1] * a.y);
    o[2] = (__bf16)((float)v[2] * a.z); o[3] = (__bf16)((float)v[3] * a.w);
    o[4] = (__bf16)((float)v[4] * c.x); o[5] = (__bf16)((float)v[5] * c.y);
    o[6] = (__bf16)((float)v[6] * c.z); o[7] = (__bf16)((float)v[7] * c.w);
    ((bf16x8*)vt)[i] = o;
}

// ---------------------------------------------------------------------------
// Kernel D: attention — BARRIER-FREE K-loop, no LDS. Computes O^T = Vt * P^T.
// Wave owns 32 q x 1024 keys. Per 32-key step:
//   QK: K A-frags loaded with PERMUTED key rows g(m)=(m>>2)*8+(m&3) (+4 for
//       tile B) -> S^T C-layout lands lane (quad Q, l15) with exactly keys
//       {8Q..8Q+7} for q=l15 — the PV B-frag layout. exp2 in regs, build
//       bf16x8 directly, NO cross-lane movement.
//   PV: V A-frags = rows of Vt, contiguous bf16x8 straight from global.
// K(t+1) register-prefetched; V issued at iter top, consumed after QK.
// grid = B * (N/128) * KSEG = 512 blocks of 256 (4 independent waves).
// ---------------------------------------------------------------------------
__global__ __launch_bounds__(256, 2) void attn_kernel(
    const __bf16* __restrict__ qb, const __bf16* __restrict__ kb,
    const __bf16* __restrict__ vt, float* __restrict__ part)
{
    int idx = blockIdx.x;
    int seg = idx & (KSEG - 1);
    int qtile = (idx >> 2) & 31;          // 32 tiles of 128 q
    int b = idx >> 7;
    int w = threadIdx.x >> 6;
    int L = threadIdx.x & 63;
    int quad = L >> 4, l15 = L & 15;

    const bf16x8* qv = (const bf16x8*)(qb + (size_t)b * N_ * D_);
    const bf16x8* kv = (const bf16x8*)(kb + (size_t)b * N_ * D_);
    const __bf16* vp = vt + (size_t)b * D_ * N_;

    int q0w = qtile * 128 + w * 32;       // this wave's 32 q
    // Q B-frags (resident): B[n=q][k=d], lane l15 = q row
    bf16x8 bq[2][4];
#pragma unroll
    for (int s = 0; s < 2; ++s)
#pragma unroll
        for (int f = 0; f < 4; ++f)
            bq[s][f] = qv[(q0w + s * 16 + l15) * 16 + f * 4 + quad];

    f32x4 oacc[2][8];
#pragma unroll
    for (int s = 0; s < 2; ++s)
#pragma unroll
        for (int d = 0; d < 8; ++d) oacc[s][d] = (f32x4){0.f, 0.f, 0.f, 0.f};

    // permuted key row: tileA key g = (l15>>2)*8 + (l15&3); tileB = g+4
    int pkrow = (l15 >> 2) * 8 + (l15 & 3);
    int k0 = seg * NSEG;
    const int T = NSEG / 32;              // 32

    bf16x8 akA[4], akB[4], aknA[4], aknB[4];
#pragma unroll
    for (int f = 0; f < 4; ++f) {
        akA[f] = kv[(k0 + pkrow) * 16 + f * 4 + quad];
        akB[f] = kv[(k0 + pkrow + 4) * 16 + f * 4 + quad];
    }

    for (int t = 0; t < T; ++t) {
        int kt = k0 + t * 32;
        // V A-frags for this step: A[m=d][k=key], rows of Vt (contiguous)
        bf16x8 vfrag[8];
#pragma unroll
        for (int ds = 0; ds < 8; ++ds)
            vfrag[ds] = *(const bf16x8*)(vp + (size_t)(ds * 16 + l15) * N_ + kt + quad * 8);
        // prefetch next step's K frags (full-iteration latency cover)
        int ktn = (t + 1 < T) ? kt + 32 : kt;
#pragma unroll
        for (int f = 0; f < 4; ++f) {
            aknA[f] = kv[(ktn + pkrow) * 16 + f * 4 + quad];
            aknB[f] = kv[(ktn + pkrow + 4) * 16 + f * 4 + quad];
        }

        // QK + exp2 -> PV B-frags entirely in registers
        bf16x8 pb[2];
#pragma unroll
        for (int s = 0; s < 2; ++s) {
            f32x4 accA = {0.f, 0.f, 0.f, 0.f};
            f32x4 accB = {0.f, 0.f, 0.f, 0.f};
#pragma unroll
            for (int f = 0; f < 4; ++f) {
                accA = __builtin_amdgcn_mfma_f32_16x16x32_bf16(akA[f], bq[s][f], accA, 0, 0, 0);
                accB = __builtin_amdgcn_mfma_f32_16x16x32_bf16(akB[f], bq[s][f], accB, 0, 0, 0);
            }
            // lane holds P[q=l15][keys 8*quad + (0..3)] (A) and +4..7 (B)
            bf16x8 p;
            p[0] = (__bf16)__builtin_amdgcn_exp2f(accA[0]);
            p[1] = (__bf16)__builtin_amdgcn_exp2f(accA[1]);
            p[2] = (__bf16)__builtin_amdgcn_exp2f(accA[2]);
            p[3] = (__bf16)__builtin_amdgcn_exp2f(accA[3]);
            p[4] = (__bf16)__builtin_amdgcn_exp2f(accB[0]);
            p[5] = (__bf16)__builtin_amdgcn_exp2f(accB[1]);
            p[6] = (__bf16)__builtin_amdgcn_exp2f(accB[2]);
            p[7] = (__bf16)__builtin_amdgcn_exp2f(accB[3]);
            pb[s] = p;
        }
        // PV: O^T[d][q] += Vt-frag * P^T-frag
#pragma unroll
        for (int ds = 0; ds < 8; ++ds)
#pragma unroll
            for (int s = 0; s < 2; ++s)
                oacc[s][ds] = __builtin_amdgcn_mfma_f32_16x16x32_bf16(
                    vfrag[ds], pb[s], oacc[s][ds], 0, 0, 0);
#pragma unroll
        for (int f = 0; f < 4; ++f) { akA[f] = aknA[f]; akB[f] = aknB[f]; }
    }

    // epilogue: O^T C-layout: d = ds*16 + quad*4 + r (contiguous in r -> float4),
    // q = q0w + s*16 + l15
    float* op = part + ((size_t)seg * B_ * N_ + (size_t)b * N_ + q0w) * D_;
#pragma unroll
    for (int s = 0; s < 2; ++s)
#pragma unroll
        for (int ds = 0; ds < 8; ++ds) {
            float4 o4;
            o4.x = oacc[s][ds][0]; o4.y = oacc[s][ds][1];
            o4.z = oacc[s][ds][2]; o4.w = oacc[s][ds][3];
            *(float4*)(op + (size_t)(s * 16 + l15) * D_ + ds * 16 + quad * 4) = o4;
        }
}

// ---------------------------------------------------------------------------
// Kernel E: out = sum of KSEG partials
// ---------------------------------------------------------------------------
__global__ __launch_bounds__(256) void reduce_kernel(
    const float* __restrict__ part, float* __restrict__ out)
{
    int i = blockIdx.x * 256 + threadIdx.x;
    const f32x4* p = (const f32x4*)part;
    f32x4 s = p[i];
#pragma unroll
    for (int sgi = 1; sgi < KSEG; ++sgi) {
        f32x4 t = p[(size_t)sgi * (B_ * N_ * D_ / 4) + i];
        s[0] += t[0]; s[1] += t[1]; s[2] += t[2]; s[3] += t[3];
    }
    ((f32x4*)out)[i] = s;
}

extern "C" void kernel_launch(void* const* d_in, const int* in_sizes, int n_in,
                              void* d_out, int out_size, void* d_ws, size_t ws_size,
                              hipStream_t stream) {
    const float* q = (const float*)d_in[0];
    const float* k = (const float*)d_in[1];
    const float* v = (const float*)d_in[2];
    float* out = (float*)d_out;
    char* ws = (char*)d_ws;
    __bf16* qb = (__bf16*)(ws);
    __bf16* kb = (__bf16*)(ws + OFF_KB);
    __bf16* vt = (__bf16*)(ws + OFF_VT);
    float* l    = (float*)(ws + OFF_L);
    float* linv = (float*)(ws + OFF_LINV);
    float* part = (float*)(ws + OFF_PART);

    hipLaunchKernelGGL(cvt_kernel, dim3(6144), dim3(256), 0, stream, q, k, v, qb, kb, vt);
    hipMemsetAsync(l, 0, (size_t)B_ * N_ * sizeof(float), stream);
    hipLaunchKernelGGL(stats_kernel, dim3(B_ * (N_ / 128) * QSEG), dim3(256), 0, stream, qb, kb, l);
    hipLaunchKernelGGL(recip_kernel, dim3(B_ * N_ / 256), dim3(256), 0, stream, l, linv);
    hipLaunchKernelGGL(scalev_kernel, dim3(B_ * D_ * N_ / 8 / 256), dim3(256), 0, stream, linv, vt);
    hipLaunchKernelGGL(attn_kernel, dim3(B_ * (N_ / 128) * KSEG), dim3(256), 0, stream, qb, kb, vt, part);
    hipLaunchKernelGGL(reduce_kernel, dim3(B_ * N_ * D_ / 4 / 256), dim3(256), 0, stream, part, out);
}

// Round 8
// 209.747 us; speedup vs baseline: 1.3020x; 1.3020x over previous
//
#include <hip/hip_runtime.h>
#include <hip/hip_bf16.h>

#define B_ 4
#define N_ 4096
#define D_ 128
#define KSEG 4
#define QSEG 4

typedef __bf16 bf16x8 __attribute__((ext_vector_type(8)));
typedef float f32x4 __attribute__((ext_vector_type(4)));

// alpha = log2(e) / sqrt(128), folded into Qp at conversion time
#define ALPHA 0.12752361680972262f

// ws layout (all fragment-linear packed, 16 B per (tile,frag,lane) chunk):
//   Qp : bf16 [B][256 qstep][4 f][64 lane][8]   @ 0      (4 MiB, alpha-scaled)
//   Kp : bf16 [B][128 kb][8 slot=f*2+ab][64][8] @ 4 MiB  (permuted-key frag order)
//   Vp : bf16 [B][128 kb][8 ds][64][8]          @ 8 MiB  (linv-scaled in place)
//   l    : f32 [B][N]                           @ 12 MiB
//   linv : f32 [B][N]                           @ 12 MiB + 64 KiB
//   part : f32 [KSEG][B][N][D]                  @ 13 MiB (32 MiB)
#define OFF_KP   (4u << 20)
#define OFF_VP   (8u << 20)
#define OFF_L    (12u << 20)
#define OFF_LINV ((12u << 20) + (64u << 10))
#define OFF_PART (13u << 20)

// ---------------------------------------------------------------------------
// Kernel A: pack Q*alpha, K (permuted key order), V-transpose into fragment-
// linear layouts. One thread per 16 B output chunk; writes fully coalesced.
//   Q chunk g = ((b*256+qstep)*4+f)*64 + lane : Q[b][qstep*16+l15][(f*4+quad)*8..]
//   K chunk g = ((b*128+kb)*8+f*2+ab)*64+lane : K[b][kb*32+(l15>>2)*8+(l15&3)+ab*4][(f*4+quad)*8..]
//   V chunk g = ((b*128+kb)*8+ds)*64+lane     : V[b][kb*32+quad*8+j][ds*16+l15], j=0..8
// ---------------------------------------------------------------------------
__global__ __launch_bounds__(256) void cvt_kernel(
    const float* __restrict__ q, const float* __restrict__ k,
    const float* __restrict__ v,
    __bf16* __restrict__ qp, __bf16* __restrict__ kp, __bf16* __restrict__ vp)
{
    int bid = blockIdx.x;
    int g = (bid & 1023) * 256 + threadIdx.x;   // 0..262143 within section
    int lane = g & 63;
    int l15 = lane & 15, quad = lane >> 4;
    if (bid < 1024) {
        int f = (g >> 6) & 3;
        int qstep = (g >> 8) & 255;
        int b = g >> 16;
        const float* src = q + ((size_t)(b * N_ + qstep * 16 + l15) * D_ + (f * 4 + quad) * 8);
        float4 x0 = *(const float4*)src;
        float4 x1 = *(const float4*)(src + 4);
        bf16x8 y;
        y[0] = (__bf16)(x0.x * ALPHA); y[1] = (__bf16)(x0.y * ALPHA);
        y[2] = (__bf16)(x0.z * ALPHA); y[3] = (__bf16)(x0.w * ALPHA);
        y[4] = (__bf16)(x1.x * ALPHA); y[5] = (__bf16)(x1.y * ALPHA);
        y[6] = (__bf16)(x1.z * ALPHA); y[7] = (__bf16)(x1.w * ALPHA);
        ((bf16x8*)qp)[g] = y;
    } else if (bid < 2048) {
        int slot = (g >> 6) & 7;
        int kb = (g >> 9) & 127;
        int b = g >> 16;
        int f = slot >> 1, ab = slot & 1;
        int row = kb * 32 + (l15 >> 2) * 8 + (l15 & 3) + ab * 4;
        const float* src = k + ((size_t)(b * N_ + row) * D_ + (f * 4 + quad) * 8);
        float4 x0 = *(const float4*)src;
        float4 x1 = *(const float4*)(src + 4);
        bf16x8 y;
        y[0] = (__bf16)x0.x; y[1] = (__bf16)x0.y; y[2] = (__bf16)x0.z; y[3] = (__bf16)x0.w;
        y[4] = (__bf16)x1.x; y[5] = (__bf16)x1.y; y[6] = (__bf16)x1.z; y[7] = (__bf16)x1.w;
        ((bf16x8*)kp)[g] = y;
    } else {
        int ds = (g >> 6) & 7;
        int kb = (g >> 9) & 127;
        int b = g >> 16;
        int d = ds * 16 + l15;
        int k0 = kb * 32 + quad * 8;
        const float* src = v + ((size_t)(b * N_ + k0) * D_ + d);
        bf16x8 y;
#pragma unroll
        for (int j = 0; j < 8; ++j)
            y[j] = (__bf16)src[(size_t)j * D_];
        ((bf16x8*)vp)[g] = y;
    }
}

// ---------------------------------------------------------------------------
// Kernel B: column stats — barrier-free, LDS-free, fully-coalesced frag loads.
// Wave owns 32 keys (one kb block, permuted order), loops 16-q steps with
// packed-Q B-frags, register prefetch. grid = B*32*QSEG = 512 blocks of 256.
// ---------------------------------------------------------------------------
__global__ __launch_bounds__(256, 4) void stats_kernel(
    const __bf16* __restrict__ qp, const __bf16* __restrict__ kp,
    float* __restrict__ l)
{
    int idx = blockIdx.x;
    int qseg = idx & (QSEG - 1);
    int kb4 = (idx >> 2) & 31;
    int b = idx >> 7;
    int w = threadIdx.x >> 6;
    int lane = threadIdx.x & 63;
    int quad = lane >> 4, l15 = lane & 15;
    int kb = kb4 * 4 + w;

    const bf16x8* kc = (const bf16x8*)kp;
    const bf16x8* qc8 = (const bf16x8*)qp;

    bf16x8 af[2][4];
#pragma unroll
    for (int ab = 0; ab < 2; ++ab)
#pragma unroll
        for (int f = 0; f < 4; ++f)
            af[ab][f] = kc[(((size_t)(b * 128 + kb) * 8) + f * 2 + ab) * 64 + lane];

    int qs0 = qseg * 64;                  // 64 q-steps of 16 per segment
    bf16x8 qcur[4], qnxt[4];
#pragma unroll
    for (int f = 0; f < 4; ++f)
        qcur[f] = qc8[((size_t)(b * 256 + qs0) * 4 + f) * 64 + lane];

    float ps[8];
#pragma unroll
    for (int s = 0; s < 8; ++s) ps[s] = 0.f;

    for (int t = 0; t < 64; ++t) {
        int tn = (t + 1 < 64) ? t + 1 : t;
#pragma unroll
        for (int f = 0; f < 4; ++f)
            qnxt[f] = qc8[((size_t)(b * 256 + qs0 + tn) * 4 + f) * 64 + lane];
#pragma unroll
        for (int ab = 0; ab < 2; ++ab) {
            f32x4 acc = {0.f, 0.f, 0.f, 0.f};
#pragma unroll
            for (int f = 0; f < 4; ++f)
                acc = __builtin_amdgcn_mfma_f32_16x16x32_bf16(af[ab][f], qcur[f], acc, 0, 0, 0);
#pragma unroll
            for (int r = 0; r < 4; ++r)
                ps[ab * 4 + r] += __builtin_amdgcn_exp2f(acc[r]);
        }
#pragma unroll
        for (int f = 0; f < 4; ++f) qcur[f] = qnxt[f];
    }
    // reduce over the 16 q-columns (lanes sharing a quad)
#pragma unroll
    for (int m = 1; m <= 8; m <<= 1)
#pragma unroll
        for (int s = 0; s < 8; ++s)
            ps[s] += __shfl_xor(ps[s], m, 64);
    if (l15 == 0) {
        // permuted C rows: key = kb*32 + quad*8 + ab*4 + r
        float* dst = l + (size_t)b * N_ + kb * 32 + quad * 8;
#pragma unroll
        for (int ab = 0; ab < 2; ++ab)
#pragma unroll
            for (int r = 0; r < 4; ++r)
                atomicAdd(dst + ab * 4 + r, ps[ab * 4 + r]);
    }
}

// ---------------------------------------------------------------------------
// Kernel C: linv = 1/l
// ---------------------------------------------------------------------------
__global__ __launch_bounds__(256) void recip_kernel(
    const float* __restrict__ l, float* __restrict__ linv)
{
    int i = blockIdx.x * 256 + threadIdx.x;
    linv[i] = 1.f / l[i];
}

// ---------------------------------------------------------------------------
// Kernel C2: Vp chunk (b,kb,ds,lane) *= linv[b][kb*32 + quad*8 .. +8]
// ---------------------------------------------------------------------------
__global__ __launch_bounds__(256) void scalev_kernel(
    const float* __restrict__ linv, __bf16* __restrict__ vp)
{
    int i = blockIdx.x * 256 + threadIdx.x;  // chunk index, 262144 total
    int lane = i & 63;
    int kb = (i >> 9) & 127;
    int b = i >> 16;
    int quad = lane >> 4;
    int k0 = kb * 32 + quad * 8;
    const float* lp = linv + (size_t)b * N_ + k0;
    float4 a = *(const float4*)lp;
    float4 c = *(const float4*)(lp + 4);
    bf16x8 v = ((const bf16x8*)vp)[i];
    bf16x8 o;
    o[0] = (__bf16)((float)v[0] * a.x); o[1] = (__bf16)((float)v[1] * a.y);
    o[2] = (__bf16)((float)v[2] * a.z); o[3] = (__bf16)((float)v[3] * a.w);
    o[4] = (__bf16)((float)v[4] * c.x); o[5] = (__bf16)((float)v[5] * c.y);
    o[6] = (__bf16)((float)v[6] * c.z); o[7] = (__bf16)((float)v[7] * c.w);
    ((bf16x8*)vp)[i] = o;
}

// ---------------------------------------------------------------------------
// Kernel D: attention — barrier-free, LDS-free (R7 structure, proven correct)
// with fully-coalesced packed frag loads. O^T = Vp * P^T; P built in regs via
// the permuted-key trick. Wave owns 32 q x 1024 keys.
// grid = B * 32 * KSEG = 512 blocks of 256.
// ---------------------------------------------------------------------------
__global__ __launch_bounds__(256, 2) void attn_kernel(
    const __bf16* __restrict__ qp, const __bf16* __restrict__ kp,
    const __bf16* __restrict__ vp, float* __restrict__ part)
{
    int idx = blockIdx.x;
    int seg = idx & (KSEG - 1);
    int qtile = (idx >> 2) & 31;          // 32 tiles of 128 q
    int b = idx >> 7;
    int w = threadIdx.x >> 6;
    int lane = threadIdx.x & 63;
    int quad = lane >> 4, l15 = lane & 15;

    const bf16x8* qc8 = (const bf16x8*)qp;
    const bf16x8* kc = (const bf16x8*)kp;
    const bf16x8* vc = (const bf16x8*)vp;

    int q0w = qtile * 128 + w * 32;       // this wave's 32 q
    int qstep0 = qtile * 8 + w * 2;
    bf16x8 bq[2][4];
#pragma unroll
    for (int s = 0; s < 2; ++s)
#pragma unroll
        for (int f = 0; f < 4; ++f)
            bq[s][f] = qc8[((size_t)(b * 256 + qstep0 + s) * 4 + f) * 64 + lane];

    f32x4 oacc[2][8];
#pragma unroll
    for (int s = 0; s < 2; ++s)
#pragma unroll
        for (int d = 0; d < 8; ++d) oacc[s][d] = (f32x4){0.f, 0.f, 0.f, 0.f};

    int kb0 = seg * 32;
    bf16x8 akA[4], akB[4], aknA[4], aknB[4];
#pragma unroll
    for (int f = 0; f < 4; ++f) {
        akA[f] = kc[(((size_t)(b * 128 + kb0) * 8) + f * 2 + 0) * 64 + lane];
        akB[f] = kc[(((size_t)(b * 128 + kb0) * 8) + f * 2 + 1) * 64 + lane];
    }

    for (int t = 0; t < 32; ++t) {
        int kb = kb0 + t;
        // V A-frags: one fully-coalesced 1 KB load per ds
        bf16x8 vfrag[8];
#pragma unroll
        for (int ds = 0; ds < 8; ++ds)
            vfrag[ds] = vc[(((size_t)(b * 128 + kb) * 8) + ds) * 64 + lane];
        // prefetch next step's K frags
        int kbn = (t + 1 < 32) ? kb + 1 : kb;
#pragma unroll
        for (int f = 0; f < 4; ++f) {
            aknA[f] = kc[(((size_t)(b * 128 + kbn) * 8) + f * 2 + 0) * 64 + lane];
            aknB[f] = kc[(((size_t)(b * 128 + kbn) * 8) + f * 2 + 1) * 64 + lane];
        }

        // QK + exp2 -> PV B-frags entirely in registers (R7-proven mapping)
        bf16x8 pb[2];
#pragma unroll
        for (int s = 0; s < 2; ++s) {
            f32x4 accA = {0.f, 0.f, 0.f, 0.f};
            f32x4 accB = {0.f, 0.f, 0.f, 0.f};
#pragma unroll
            for (int f = 0; f < 4; ++f) {
                accA = __builtin_amdgcn_mfma_f32_16x16x32_bf16(akA[f], bq[s][f], accA, 0, 0, 0);
                accB = __builtin_amdgcn_mfma_f32_16x16x32_bf16(akB[f], bq[s][f], accB, 0, 0, 0);
            }
            bf16x8 p;
            p[0] = (__bf16)__builtin_amdgcn_exp2f(accA[0]);
            p[1] = (__bf16)__builtin_amdgcn_exp2f(accA[1]);
            p[2] = (__bf16)__builtin_amdgcn_exp2f(accA[2]);
            p[3] = (__bf16)__builtin_amdgcn_exp2f(accA[3]);
            p[4] = (__bf16)__builtin_amdgcn_exp2f(accB[0]);
            p[5] = (__bf16)__builtin_amdgcn_exp2f(accB[1]);
            p[6] = (__bf16)__builtin_amdgcn_exp2f(accB[2]);
            p[7] = (__bf16)__builtin_amdgcn_exp2f(accB[3]);
            pb[s] = p;
        }
#pragma unroll
        for (int ds = 0; ds < 8; ++ds)
#pragma unroll
            for (int s = 0; s < 2; ++s)
                oacc[s][ds] = __builtin_amdgcn_mfma_f32_16x16x32_bf16(
                    vfrag[ds], pb[s], oacc[s][ds], 0, 0, 0);
#pragma unroll
        for (int f = 0; f < 4; ++f) { akA[f] = aknA[f]; akB[f] = aknB[f]; }
    }

    // epilogue: d = ds*16 + quad*4 + r (float4), q = q0w + s*16 + l15
    float* op = part + ((size_t)seg * B_ * N_ + (size_t)b * N_ + q0w) * D_;
#pragma unroll
    for (int s = 0; s < 2; ++s)
#pragma unroll
        for (int ds = 0; ds < 8; ++ds) {
            float4 o4;
            o4.x = oacc[s][ds][0]; o4.y = oacc[s][ds][1];
            o4.z = oacc[s][ds][2]; o4.w = oacc[s][ds][3];
            *(float4*)(op + (size_t)(s * 16 + l15) * D_ + ds * 16 + quad * 4) = o4;
        }
}

// ---------------------------------------------------------------------------
// Kernel E: out = sum of KSEG partials
// ---------------------------------------------------------------------------
__global__ __launch_bounds__(256) void reduce_kernel(
    const float* __restrict__ part, float* __restrict__ out)
{
    int i = blockIdx.x * 256 + threadIdx.x;
    const f32x4* p = (const f32x4*)part;
    f32x4 s = p[i];
#pragma unroll
    for (int sgi = 1; sgi < KSEG; ++sgi) {
        f32x4 t = p[(size_t)sgi * (B_ * N_ * D_ / 4) + i];
        s[0] += t[0]; s[1] += t[1]; s[2] += t[2]; s[3] += t[3];
    }
    ((f32x4*)out)[i] = s;
}

extern "C" void kernel_launch(void* const* d_in, const int* in_sizes, int n_in,
                              void* d_out, int out_size, void* d_ws, size_t ws_size,
                              hipStream_t stream) {
    const float* q = (const float*)d_in[0];
    const float* k = (const float*)d_in[1];
    const float* v = (const float*)d_in[2];
    float* out = (float*)d_out;
    char* ws = (char*)d_ws;
    __bf16* qp = (__bf16*)(ws);
    __bf16* kp = (__bf16*)(ws + OFF_KP);
    __bf16* vp = (__bf16*)(ws + OFF_VP);
    float* l    = (float*)(ws + OFF_L);
    float* linv = (float*)(ws + OFF_LINV);
    float* part = (float*)(ws + OFF_PART);

    hipLaunchKernelGGL(cvt_kernel, dim3(3072), dim3(256), 0, stream, q, k, v, qp, kp, vp);
    hipMemsetAsync(l, 0, (size_t)B_ * N_ * sizeof(float), stream);
    hipLaunchKernelGGL(stats_kernel, dim3(B_ * 32 * QSEG), dim3(256), 0, stream, qp, kp, l);
    hipLaunchKernelGGL(recip_kernel, dim3(B_ * N_ / 256), dim3(256), 0, stream, l, linv);
    hipLaunchKernelGGL(scalev_kernel, dim3(1024), dim3(256), 0, stream, linv, vp);
    hipLaunchKernelGGL(attn_kernel, dim3(B_ * 32 * KSEG), dim3(256), 0, stream, qp, kp, vp, part);
    hipLaunchKernelGGL(reduce_kernel, dim3(B_ * N_ * D_ / 4 / 256), dim3(256), 0, stream, part, out);
}

// Round 9
// 142.780 us; speedup vs baseline: 1.9126x; 1.4690x over previous
//
#include <hip/hip_runtime.h>
#include <hip/hip_bf16.h>

#define B_ 4
#define N_ 4096
#define D_ 128
#define KSEG 4
#define QSEG 4

typedef __bf16 bf16x8 __attribute__((ext_vector_type(8)));
typedef float f32x4 __attribute__((ext_vector_type(4)));

// alpha = log2(e) / sqrt(128), folded into Qp at conversion time
#define ALPHA 0.12752361680972262f

// ws layout (all fragment-linear packed, 16 B per (tile,frag,lane) chunk):
//   Qp : bf16 [B][256 qstep][4 f][64 lane][8]   @ 0      (4 MiB, alpha-scaled)
//   Kp : bf16 [B][128 kb][8 slot=f*2+ab][64][8] @ 4 MiB  (permuted-key frag order)
//   Vp : bf16 [B][128 kb][8 ds][64][8]          @ 8 MiB  (linv-scaled in place)
//   l    : f32 [B][N]                           @ 12 MiB
//   linv : f32 [B][N]                           @ 12 MiB + 64 KiB
//   part : f32 [KSEG][B][N][D]                  @ 13 MiB (32 MiB)
#define OFF_KP   (4u << 20)
#define OFF_VP   (8u << 20)
#define OFF_L    (12u << 20)
#define OFF_LINV ((12u << 20) + (64u << 10))
#define OFF_PART (13u << 20)

// ---------------------------------------------------------------------------
// Kernel A: pack Q*alpha, K (permuted key order), V-transpose into fragment-
// linear layouts. One thread per 16 B output chunk; writes fully coalesced.
// ---------------------------------------------------------------------------
__global__ __launch_bounds__(256) void cvt_kernel(
    const float* __restrict__ q, const float* __restrict__ k,
    const float* __restrict__ v,
    __bf16* __restrict__ qp, __bf16* __restrict__ kp, __bf16* __restrict__ vp)
{
    int bid = blockIdx.x;
    int g = (bid & 1023) * 256 + threadIdx.x;   // 0..262143 within section
    int lane = g & 63;
    int l15 = lane & 15, quad = lane >> 4;
    if (bid < 1024) {
        int f = (g >> 6) & 3;
        int qstep = (g >> 8) & 255;
        int b = g >> 16;
        const float* src = q + ((size_t)(b * N_ + qstep * 16 + l15) * D_ + (f * 4 + quad) * 8);
        float4 x0 = *(const float4*)src;
        float4 x1 = *(const float4*)(src + 4);
        bf16x8 y;
        y[0] = (__bf16)(x0.x * ALPHA); y[1] = (__bf16)(x0.y * ALPHA);
        y[2] = (__bf16)(x0.z * ALPHA); y[3] = (__bf16)(x0.w * ALPHA);
        y[4] = (__bf16)(x1.x * ALPHA); y[5] = (__bf16)(x1.y * ALPHA);
        y[6] = (__bf16)(x1.z * ALPHA); y[7] = (__bf16)(x1.w * ALPHA);
        ((bf16x8*)qp)[g] = y;
    } else if (bid < 2048) {
        int slot = (g >> 6) & 7;
        int kb = (g >> 9) & 127;
        int b = g >> 16;
        int f = slot >> 1, ab = slot & 1;
        int row = kb * 32 + (l15 >> 2) * 8 + (l15 & 3) + ab * 4;
        const float* src = k + ((size_t)(b * N_ + row) * D_ + (f * 4 + quad) * 8);
        float4 x0 = *(const float4*)src;
        float4 x1 = *(const float4*)(src + 4);
        bf16x8 y;
        y[0] = (__bf16)x0.x; y[1] = (__bf16)x0.y; y[2] = (__bf16)x0.z; y[3] = (__bf16)x0.w;
        y[4] = (__bf16)x1.x; y[5] = (__bf16)x1.y; y[6] = (__bf16)x1.z; y[7] = (__bf16)x1.w;
        ((bf16x8*)kp)[g] = y;
    } else {
        int ds = (g >> 6) & 7;
        int kb = (g >> 9) & 127;
        int b = g >> 16;
        int d = ds * 16 + l15;
        int k0 = kb * 32 + quad * 8;
        const float* src = v + ((size_t)(b * N_ + k0) * D_ + d);
        bf16x8 y;
#pragma unroll
        for (int j = 0; j < 8; ++j)
            y[j] = (__bf16)src[(size_t)j * D_];
        ((bf16x8*)vp)[g] = y;
    }
}

// ---------------------------------------------------------------------------
// Kernel B: column stats with LDS-shared Q tiles. Block = 4 waves, wave w owns
// 32 keys (kb = kb4*4+w, A-frags resident). Per iter: stage 4 q-steps (16
// chunks, wave w stages q-step j=w's 4 f-chunks) via reg->ds_write dbuf
// (R5-proven single-barrier), then 32 MFMA + 32 exp2 per wave from LDS.
// Q tile read ONCE per block instead of once per wave: L2 traffic /4.
// grid = B * 32 * QSEG = 512 blocks of 256.
// ---------------------------------------------------------------------------
__global__ __launch_bounds__(256, 2) void stats_kernel(
    const __bf16* __restrict__ qp, const __bf16* __restrict__ kp,
    float* __restrict__ l)
{
    __shared__ __bf16 lds[2][16 * 512];   // 2 x 16 KiB, 16 chunks of 1 KiB

    int idx = blockIdx.x;
    int qseg = idx & (QSEG - 1);
    int kb4 = (idx >> 2) & 31;
    int b = idx >> 7;
    int w = threadIdx.x >> 6;
    int lane = threadIdx.x & 63;
    int quad = lane >> 4, l15 = lane & 15;
    int kb = kb4 * 4 + w;

    const bf16x8* kc = (const bf16x8*)kp;
    const bf16x8* qc8 = (const bf16x8*)qp;

    bf16x8 af[2][4];
#pragma unroll
    for (int ab = 0; ab < 2; ++ab)
#pragma unroll
        for (int f = 0; f < 4; ++f)
            af[ab][f] = kc[(((size_t)(b * 128 + kb) * 8) + f * 2 + ab) * 64 + lane];

    int qs0 = qseg * 64;                  // 64 q-steps per segment, 16 iters of 4
    bf16x8 st[4];
#pragma unroll
    for (int f = 0; f < 4; ++f)
        st[f] = qc8[((size_t)(b * 256 + qs0 + w) * 4 + f) * 64 + lane];

    float ps[8];
#pragma unroll
    for (int s = 0; s < 8; ++s) ps[s] = 0.f;

    for (int t = 0; t < 16; ++t) {
        __bf16* buf = &lds[t & 1][0];
        // commit tile t (wave w -> chunks w*4+f); safe: readers of this buffer
        // (iter t-2) all completed before the PREVIOUS barrier
#pragma unroll
        for (int f = 0; f < 4; ++f)
            *(bf16x8*)(buf + (w * 4 + f) * 512 + lane * 8) = st[f];
        // prefetch tile t+1
        int tn = (t + 1 < 16) ? t + 1 : t;
#pragma unroll
        for (int f = 0; f < 4; ++f)
            st[f] = qc8[((size_t)(b * 256 + qs0 + tn * 4 + w) * 4 + f) * 64 + lane];
        __syncthreads();                  // tile t visible to all waves
#pragma unroll
        for (int j = 0; j < 4; ++j) {
            bf16x8 qf[4];
#pragma unroll
            for (int f = 0; f < 4; ++f)
                qf[f] = *(const bf16x8*)(buf + (j * 4 + f) * 512 + lane * 8);
#pragma unroll
            for (int ab = 0; ab < 2; ++ab) {
                f32x4 acc = {0.f, 0.f, 0.f, 0.f};
#pragma unroll
                for (int f = 0; f < 4; ++f)
                    acc = __builtin_amdgcn_mfma_f32_16x16x32_bf16(af[ab][f], qf[f], acc, 0, 0, 0);
#pragma unroll
                for (int r = 0; r < 4; ++r)
                    ps[ab * 4 + r] += __builtin_amdgcn_exp2f(acc[r]);
            }
        }
    }
    // reduce over the 16 q-columns (lanes sharing a quad)
#pragma unroll
    for (int m = 1; m <= 8; m <<= 1)
#pragma unroll
        for (int s = 0; s < 8; ++s)
            ps[s] += __shfl_xor(ps[s], m, 64);
    if (l15 == 0) {
        // permuted C rows: key = kb*32 + quad*8 + ab*4 + r
        float* dst = l + (size_t)b * N_ + kb * 32 + quad * 8;
#pragma unroll
        for (int ab = 0; ab < 2; ++ab)
#pragma unroll
            for (int r = 0; r < 4; ++r)
                atomicAdd(dst + ab * 4 + r, ps[ab * 4 + r]);
    }
}

// ---------------------------------------------------------------------------
// Kernel C: linv = 1/l
// ---------------------------------------------------------------------------
__global__ __launch_bounds__(256) void recip_kernel(
    const float* __restrict__ l, float* __restrict__ linv)
{
    int i = blockIdx.x * 256 + threadIdx.x;
    linv[i] = 1.f / l[i];
}

// ---------------------------------------------------------------------------
// Kernel C2: Vp chunk (b,kb,ds,lane) *= linv[b][kb*32 + quad*8 .. +8]
// ---------------------------------------------------------------------------
__global__ __launch_bounds__(256) void scalev_kernel(
    const float* __restrict__ linv, __bf16* __restrict__ vp)
{
    int i = blockIdx.x * 256 + threadIdx.x;  // chunk index, 262144 total
    int lane = i & 63;
    int kb = (i >> 9) & 127;
    int b = i >> 16;
    int quad = lane >> 4;
    int k0 = kb * 32 + quad * 8;
    const float* lp = linv + (size_t)b * N_ + k0;
    float4 a = *(const float4*)lp;
    float4 c = *(const float4*)(lp + 4);
    bf16x8 v = ((const bf16x8*)vp)[i];
    bf16x8 o;
    o[0] = (__bf16)((float)v[0] * a.x); o[1] = (__bf16)((float)v[1] * a.y);
    o[2] = (__bf16)((float)v[2] * a.z); o[3] = (__bf16)((float)v[3] * a.w);
    o[4] = (__bf16)((float)v[4] * c.x); o[5] = (__bf16)((float)v[5] * c.y);
    o[6] = (__bf16)((float)v[6] * c.z); o[7] = (__bf16)((float)v[7] * c.w);
    ((bf16x8*)vp)[i] = o;
}

// ---------------------------------------------------------------------------
// Kernel D: attention with LDS-shared K+V tiles. R8's register-P core kept
// byte-identical; the 16 KB (K,V) tile per key-step is now staged ONCE per
// block (wave w stages chunks 4w..4w+3) via reg->ds_write dbuf, single
// barrier per iter, and all 4 waves read frags from LDS (linear b128, zero
// conflicts). L2 traffic: 1.07 GB -> 268 MB.
// grid = B * 32 * KSEG = 512 blocks of 256 (2 blocks/CU).
// ---------------------------------------------------------------------------
__global__ __launch_bounds__(256, 2) void attn_kernel(
    const __bf16* __restrict__ qp, const __bf16* __restrict__ kp,
    const __bf16* __restrict__ vp, float* __restrict__ part)
{
    __shared__ __bf16 lds[2][16 * 512];   // 2 x 16 KiB: chunks 0-7 K, 8-15 V

    int idx = blockIdx.x;
    int seg = idx & (KSEG - 1);
    int qtile = (idx >> 2) & 31;          // 32 tiles of 128 q
    int b = idx >> 7;
    int w = threadIdx.x >> 6;
    int lane = threadIdx.x & 63;
    int quad = lane >> 4, l15 = lane & 15;

    const bf16x8* qc8 = (const bf16x8*)qp;
    const bf16x8* kc = (const bf16x8*)kp;
    const bf16x8* vc = (const bf16x8*)vp;

    int q0w = qtile * 128 + w * 32;       // this wave's 32 q
    int qstep0 = qtile * 8 + w * 2;
    bf16x8 bq[2][4];
#pragma unroll
    for (int s = 0; s < 2; ++s)
#pragma unroll
        for (int f = 0; f < 4; ++f)
            bq[s][f] = qc8[((size_t)(b * 256 + qstep0 + s) * 4 + f) * 64 + lane];

    f32x4 oacc[2][8];
#pragma unroll
    for (int s = 0; s < 2; ++s)
#pragma unroll
        for (int d = 0; d < 8; ++d) oacc[s][d] = (f32x4){0.f, 0.f, 0.f, 0.f};

    int kb0 = seg * 32;
    // staging regs: wave w owns chunks [4w, 4w+4) of the 16-chunk tile
    bf16x8 st[4];
#pragma unroll
    for (int i = 0; i < 4; ++i) {
        int c = w * 4 + i;
        st[i] = (c < 8) ? kc[(((size_t)(b * 128 + kb0) * 8) + c) * 64 + lane]
                        : vc[(((size_t)(b * 128 + kb0) * 8) + (c - 8)) * 64 + lane];
    }

    for (int t = 0; t < 32; ++t) {
        __bf16* buf = &lds[t & 1][0];
        // commit tile t (readers of this buffer finished before previous barrier)
#pragma unroll
        for (int i = 0; i < 4; ++i)
            *(bf16x8*)(buf + (w * 4 + i) * 512 + lane * 8) = st[i];
        // prefetch tile t+1
        int kbn = kb0 + ((t + 1 < 32) ? t + 1 : t);
#pragma unroll
        for (int i = 0; i < 4; ++i) {
            int c = w * 4 + i;
            st[i] = (c < 8) ? kc[(((size_t)(b * 128 + kbn) * 8) + c) * 64 + lane]
                            : vc[(((size_t)(b * 128 + kbn) * 8) + (c - 8)) * 64 + lane];
        }
        __syncthreads();                  // tile t visible

        // K frags from LDS (values identical to R8's direct loads)
        bf16x8 akA[4], akB[4];
#pragma unroll
        for (int f = 0; f < 4; ++f) {
            akA[f] = *(const bf16x8*)(buf + (f * 2 + 0) * 512 + lane * 8);
            akB[f] = *(const bf16x8*)(buf + (f * 2 + 1) * 512 + lane * 8);
        }
        // QK + exp2 -> PV B-frags entirely in registers (R7/R8-proven mapping)
        bf16x8 pb[2];
#pragma unroll
        for (int s = 0; s < 2; ++s) {
            f32x4 accA = {0.f, 0.f, 0.f, 0.f};
            f32x4 accB = {0.f, 0.f, 0.f, 0.f};
#pragma unroll
            for (int f = 0; f < 4; ++f) {
                accA = __builtin_amdgcn_mfma_f32_16x16x32_bf16(akA[f], bq[s][f], accA, 0, 0, 0);
                accB = __builtin_amdgcn_mfma_f32_16x16x32_bf16(akB[f], bq[s][f], accB, 0, 0, 0);
            }
            bf16x8 p;
            p[0] = (__bf16)__builtin_amdgcn_exp2f(accA[0]);
            p[1] = (__bf16)__builtin_amdgcn_exp2f(accA[1]);
            p[2] = (__bf16)__builtin_amdgcn_exp2f(accA[2]);
            p[3] = (__bf16)__builtin_amdgcn_exp2f(accA[3]);
            p[4] = (__bf16)__builtin_amdgcn_exp2f(accB[0]);
            p[5] = (__bf16)__builtin_amdgcn_exp2f(accB[1]);
            p[6] = (__bf16)__builtin_amdgcn_exp2f(accB[2]);
            p[7] = (__bf16)__builtin_amdgcn_exp2f(accB[3]);
            pb[s] = p;
        }
        // PV: V A-frags from LDS
#pragma unroll
        for (int ds = 0; ds < 8; ++ds) {
            bf16x8 vf = *(const bf16x8*)(buf + (8 + ds) * 512 + lane * 8);
#pragma unroll
            for (int s = 0; s < 2; ++s)
                oacc[s][ds] = __builtin_amdgcn_mfma_f32_16x16x32_bf16(
                    vf, pb[s], oacc[s][ds], 0, 0, 0);
        }
    }

    // epilogue: d = ds*16 + quad*4 + r (float4), q = q0w + s*16 + l15
    float* op = part + ((size_t)seg * B_ * N_ + (size_t)b * N_ + q0w) * D_;
#pragma unroll
    for (int s = 0; s < 2; ++s)
#pragma unroll
        for (int ds = 0; ds < 8; ++ds) {
            float4 o4;
            o4.x = oacc[s][ds][0]; o4.y = oacc[s][ds][1];
            o4.z = oacc[s][ds][2]; o4.w = oacc[s][ds][3];
            *(float4*)(op + (size_t)(s * 16 + l15) * D_ + ds * 16 + quad * 4) = o4;
        }
}

// ---------------------------------------------------------------------------
// Kernel E: out = sum of KSEG partials
// ---------------------------------------------------------------------------
__global__ __launch_bounds__(256) void reduce_kernel(
    const float* __restrict__ part, float* __restrict__ out)
{
    int i = blockIdx.x * 256 + threadIdx.x;
    const f32x4* p = (const f32x4*)part;
    f32x4 s = p[i];
#pragma unroll
    for (int sgi = 1; sgi < KSEG; ++sgi) {
        f32x4 t = p[(size_t)sgi * (B_ * N_ * D_ / 4) + i];
        s[0] += t[0]; s[1] += t[1]; s[2] += t[2]; s[3] += t[3];
    }
    ((f32x4*)out)[i] = s;
}

extern "C" void kernel_launch(void* const* d_in, const int* in_sizes, int n_in,
                              void* d_out, int out_size, void* d_ws, size_t ws_size,
                              hipStream_t stream) {
    const float* q = (const float*)d_in[0];
    const float* k = (const float*)d_in[1];
    const float* v = (const float*)d_in[2];
    float* out = (float*)d_out;
    char* ws = (char*)d_ws;
    __bf16* qp = (__bf16*)(ws);
    __bf16* kp = (__bf16*)(ws + OFF_KP);
    __bf16* vp = (__bf16*)(ws + OFF_VP);
    float* l    = (float*)(ws + OFF_L);
    float* linv = (float*)(ws + OFF_LINV);
    float* part = (float*)(ws + OFF_PART);

    hipLaunchKernelGGL(cvt_kernel, dim3(3072), dim3(256), 0, stream, q, k, v, qp, kp, vp);
    hipMemsetAsync(l, 0, (size_t)B_ * N_ * sizeof(float), stream);
    hipLaunchKernelGGL(stats_kernel, dim3(B_ * 32 * QSEG), dim3(256), 0, stream, qp, kp, l);
    hipLaunchKernelGGL(recip_kernel, dim3(B_ * N_ / 256), dim3(256), 0, stream, l, linv);
    hipLaunchKernelGGL(scalev_kernel, dim3(1024), dim3(256), 0, stream, linv, vp);
    hipLaunchKernelGGL(attn_kernel, dim3(B_ * 32 * KSEG), dim3(256), 0, stream, qp, kp, vp, part);
    hipLaunchKernelGGL(reduce_kernel, dim3(B_ * N_ * D_ / 4 / 256), dim3(256), 0, stream, part, out);
}

// Round 10
// 141.857 us; speedup vs baseline: 1.9250x; 1.0065x over previous
//
#include <hip/hip_runtime.h>
#include <hip/hip_bf16.h>

#define B_ 4
#define N_ 4096
#define D_ 128
#define KSEG 4
#define QSEG 8

typedef __bf16 bf16x8 __attribute__((ext_vector_type(8)));
typedef float f32x4 __attribute__((ext_vector_type(4)));

// alpha = log2(e) / sqrt(128), folded into Qp at conversion time
#define ALPHA 0.12752361680972262f

// ws layout (all fragment-linear packed, 16 B per (tile,frag,lane) chunk):
//   Qp : bf16 [B][256 qstep][4 f][64 lane][8]   @ 0      (4 MiB, alpha-scaled)
//   Kp : bf16 [B][128 kb][8 slot=f*2+ab][64][8] @ 4 MiB  (permuted-key frag order)
//   Vp : bf16 [B][128 kb][8 ds][64][8]          @ 8 MiB  (1/l folded in place)
//   l    : f32 [B][N]                           @ 12 MiB
//   part : f32 [KSEG][B][N][D]                  @ 13 MiB (32 MiB)
#define OFF_KP   (4u << 20)
#define OFF_VP   (8u << 20)
#define OFF_L    (12u << 20)
#define OFF_PART (13u << 20)

// ---------------------------------------------------------------------------
// Kernel A: pack Q*alpha, K (permuted key order), V-transpose into fragment-
// linear layouts. Q/K sections: one thread per 16 B chunk, coalesced both
// sides. V section: per-(b,kb) block does coalesced float4 row reads ->
// LDS (stride 129: quad stride 1032 mod 32 = 8 -> <=2-way, free) -> packed
// bf16x8 chunk writes. Output bytes identical to R8/R9 cvt.
// ---------------------------------------------------------------------------
__global__ __launch_bounds__(256) void cvt_kernel(
    const float* __restrict__ q, const float* __restrict__ k,
    const float* __restrict__ v,
    __bf16* __restrict__ qp, __bf16* __restrict__ kp, __bf16* __restrict__ vp)
{
    __shared__ float vl[32 * 129];   // 16.5 KiB (V section only)

    int bid = blockIdx.x;
    int tid = threadIdx.x;
    if (bid < 2048) {
        int g = (bid & 1023) * 256 + tid;   // 0..262143 within section
        int lane = g & 63;
        int l15 = lane & 15, quad = lane >> 4;
        if (bid < 1024) {
            int f = (g >> 6) & 3;
            int qstep = (g >> 8) & 255;
            int b = g >> 16;
            const float* src = q + ((size_t)(b * N_ + qstep * 16 + l15) * D_ + (f * 4 + quad) * 8);
            float4 x0 = *(const float4*)src;
            float4 x1 = *(const float4*)(src + 4);
            bf16x8 y;
            y[0] = (__bf16)(x0.x * ALPHA); y[1] = (__bf16)(x0.y * ALPHA);
            y[2] = (__bf16)(x0.z * ALPHA); y[3] = (__bf16)(x0.w * ALPHA);
            y[4] = (__bf16)(x1.x * ALPHA); y[5] = (__bf16)(x1.y * ALPHA);
            y[6] = (__bf16)(x1.z * ALPHA); y[7] = (__bf16)(x1.w * ALPHA);
            ((bf16x8*)qp)[g] = y;
        } else {
            int slot = (g >> 6) & 7;
            int kb = (g >> 9) & 127;
            int b = g >> 16;
            int f = slot >> 1, ab = slot & 1;
            int row = kb * 32 + (l15 >> 2) * 8 + (l15 & 3) + ab * 4;
            const float* src = k + ((size_t)(b * N_ + row) * D_ + (f * 4 + quad) * 8);
            float4 x0 = *(const float4*)src;
            float4 x1 = *(const float4*)(src + 4);
            bf16x8 y;
            y[0] = (__bf16)x0.x; y[1] = (__bf16)x0.y; y[2] = (__bf16)x0.z; y[3] = (__bf16)x0.w;
            y[4] = (__bf16)x1.x; y[5] = (__bf16)x1.y; y[6] = (__bf16)x1.z; y[7] = (__bf16)x1.w;
            ((bf16x8*)kp)[g] = y;
        }
    } else {
        int vb = bid - 2048;                // 0..511: one (b, kb) tile
        int b = vb >> 7, kb = vb & 127;
        const float4* src = (const float4*)(v + (size_t)(b * N_ + kb * 32) * D_);
        // read 32 rows x 128 d coalesced (1024 float4)
#pragma unroll
        for (int rep = 0; rep < 4; ++rep) {
            int i = rep * 256 + tid;
            int row = i >> 5, c4 = i & 31;
            float4 x = src[row * 32 + c4];
            float* dst = &vl[row * 129 + c4 * 4];
            dst[0] = x.x; dst[1] = x.y; dst[2] = x.z; dst[3] = x.w;
        }
        __syncthreads();
        // emit 512 packed chunks: y[j] = V[kb*32 + quad*8 + j][ds*16 + l15]
#pragma unroll
        for (int rep = 0; rep < 2; ++rep) {
            int ci = rep * 256 + tid;       // 0..511
            int ds = ci >> 6, ln = ci & 63;
            int quad = ln >> 4, l15 = ln & 15;
            bf16x8 y;
#pragma unroll
            for (int j = 0; j < 8; ++j)
                y[j] = (__bf16)vl[(quad * 8 + j) * 129 + ds * 16 + l15];
            ((bf16x8*)vp)[(((size_t)(b * 128 + kb) * 8) + ds) * 64 + ln] = y;
        }
    }
}

// ---------------------------------------------------------------------------
// Kernel B: column stats with LDS-shared Q tiles (R9-proven structure),
// QSEG=8 -> grid 1024, 4 blocks/CU, 16 waves/CU. Wave w owns 32 keys
// (kb = kb4*4+w); per iter stage 4 q-steps (wave w stages q-step j=w),
// reg->ds_write dbuf, single barrier, 32 MFMA + 32 exp2 from LDS.
// ---------------------------------------------------------------------------
__global__ __launch_bounds__(256, 4) void stats_kernel(
    const __bf16* __restrict__ qp, const __bf16* __restrict__ kp,
    float* __restrict__ l)
{
    __shared__ __bf16 lds[2][16 * 512];   // 2 x 16 KiB

    int idx = blockIdx.x;
    int qseg = idx & (QSEG - 1);
    int kb4 = (idx >> 3) & 31;
    int b = idx >> 8;
    int w = threadIdx.x >> 6;
    int lane = threadIdx.x & 63;
    int quad = lane >> 4, l15 = lane & 15;
    int kb = kb4 * 4 + w;

    const bf16x8* kc = (const bf16x8*)kp;
    const bf16x8* qc8 = (const bf16x8*)qp;

    bf16x8 af[2][4];
#pragma unroll
    for (int ab = 0; ab < 2; ++ab)
#pragma unroll
        for (int f = 0; f < 4; ++f)
            af[ab][f] = kc[(((size_t)(b * 128 + kb) * 8) + f * 2 + ab) * 64 + lane];

    int qs0 = qseg * 32;                  // 32 q-steps per segment, 8 iters of 4
    bf16x8 st[4];
#pragma unroll
    for (int f = 0; f < 4; ++f)
        st[f] = qc8[((size_t)(b * 256 + qs0 + w) * 4 + f) * 64 + lane];

    float ps[8];
#pragma unroll
    for (int s = 0; s < 8; ++s) ps[s] = 0.f;

    for (int t = 0; t < 8; ++t) {
        __bf16* buf = &lds[t & 1][0];
#pragma unroll
        for (int f = 0; f < 4; ++f)
            *(bf16x8*)(buf + (w * 4 + f) * 512 + lane * 8) = st[f];
        int tn = (t + 1 < 8) ? t + 1 : t;
#pragma unroll
        for (int f = 0; f < 4; ++f)
            st[f] = qc8[((size_t)(b * 256 + qs0 + tn * 4 + w) * 4 + f) * 64 + lane];
        __syncthreads();                  // tile t visible to all waves
#pragma unroll
        for (int j = 0; j < 4; ++j) {
            bf16x8 qf[4];
#pragma unroll
            for (int f = 0; f < 4; ++f)
                qf[f] = *(const bf16x8*)(buf + (j * 4 + f) * 512 + lane * 8);
#pragma unroll
            for (int ab = 0; ab < 2; ++ab) {
                f32x4 acc = {0.f, 0.f, 0.f, 0.f};
#pragma unroll
                for (int f = 0; f < 4; ++f)
                    acc = __builtin_amdgcn_mfma_f32_16x16x32_bf16(af[ab][f], qf[f], acc, 0, 0, 0);
#pragma unroll
                for (int r = 0; r < 4; ++r)
                    ps[ab * 4 + r] += __builtin_amdgcn_exp2f(acc[r]);
            }
        }
    }
#pragma unroll
    for (int m = 1; m <= 8; m <<= 1)
#pragma unroll
        for (int s = 0; s < 8; ++s)
            ps[s] += __shfl_xor(ps[s], m, 64);
    if (l15 == 0) {
        // permuted C rows: key = kb*32 + quad*8 + ab*4 + r
        float* dst = l + (size_t)b * N_ + kb * 32 + quad * 8;
#pragma unroll
        for (int ab = 0; ab < 2; ++ab)
#pragma unroll
            for (int r = 0; r < 4; ++r)
                atomicAdd(dst + ab * 4 + r, ps[ab * 4 + r]);
    }
}

// ---------------------------------------------------------------------------
// Kernel C2: Vp chunk (b,kb,ds,lane) *= 1/l[b][kb*32 + quad*8 .. +8]
// (recip folded in; v_rcp error ~1e-6 << bf16 eps)
// ---------------------------------------------------------------------------
__global__ __launch_bounds__(256) void scalev_kernel(
    const float* __restrict__ l, __bf16* __restrict__ vp)
{
    int i = blockIdx.x * 256 + threadIdx.x;  // chunk index, 262144 total
    int lane = i & 63;
    int kb = (i >> 9) & 127;
    int b = i >> 16;
    int quad = lane >> 4;
    int k0 = kb * 32 + quad * 8;
    const float* lp = l + (size_t)b * N_ + k0;
    float4 a = *(const float4*)lp;
    float4 c = *(const float4*)(lp + 4);
    float r0 = __builtin_amdgcn_rcpf(a.x), r1 = __builtin_amdgcn_rcpf(a.y);
    float r2 = __builtin_amdgcn_rcpf(a.z), r3 = __builtin_amdgcn_rcpf(a.w);
    float r4 = __builtin_amdgcn_rcpf(c.x), r5 = __builtin_amdgcn_rcpf(c.y);
    float r6 = __builtin_amdgcn_rcpf(c.z), r7 = __builtin_amdgcn_rcpf(c.w);
    bf16x8 v = ((const bf16x8*)vp)[i];
    bf16x8 o;
    o[0] = (__bf16)((float)v[0] * r0); o[1] = (__bf16)((float)v[1] * r1);
    o[2] = (__bf16)((float)v[2] * r2); o[3] = (__bf16)((float)v[3] * r3);
    o[4] = (__bf16)((float)v[4] * r4); o[5] = (__bf16)((float)v[5] * r5);
    o[6] = (__bf16)((float)v[6] * r6); o[7] = (__bf16)((float)v[7] * r7);
    ((bf16x8*)vp)[i] = o;
}

// ---------------------------------------------------------------------------
// Kernel D: attention with LDS-shared K+V tiles — UNCHANGED from R9 (43 µs,
// MfmaUtil 30.5%, conflicts 0). Register-P core; 16 KB tile staged once per
// block via reg->ds_write dbuf, single barrier/iter.
// grid = B * 32 * KSEG = 512 blocks of 256 (2 blocks/CU).
// ---------------------------------------------------------------------------
__global__ __launch_bounds__(256, 2) void attn_kernel(
    const __bf16* __restrict__ qp, const __bf16* __restrict__ kp,
    const __bf16* __restrict__ vp, float* __restrict__ part)
{
    __shared__ __bf16 lds[2][16 * 512];   // 2 x 16 KiB: chunks 0-7 K, 8-15 V

    int idx = blockIdx.x;
    int seg = idx & (KSEG - 1);
    int qtile = (idx >> 2) & 31;          // 32 tiles of 128 q
    int b = idx >> 7;
    int w = threadIdx.x >> 6;
    int lane = threadIdx.x & 63;
    int quad = lane >> 4, l15 = lane & 15;

    const bf16x8* qc8 = (const bf16x8*)qp;
    const bf16x8* kc = (const bf16x8*)kp;
    const bf16x8* vc = (const bf16x8*)vp;

    int q0w = qtile * 128 + w * 32;       // this wave's 32 q
    int qstep0 = qtile * 8 + w * 2;
    bf16x8 bq[2][4];
#pragma unroll
    for (int s = 0; s < 2; ++s)
#pragma unroll
        for (int f = 0; f < 4; ++f)
            bq[s][f] = qc8[((size_t)(b * 256 + qstep0 + s) * 4 + f) * 64 + lane];

    f32x4 oacc[2][8];
#pragma unroll
    for (int s = 0; s < 2; ++s)
#pragma unroll
        for (int d = 0; d < 8; ++d) oacc[s][d] = (f32x4){0.f, 0.f, 0.f, 0.f};

    int kb0 = seg * 32;
    bf16x8 st[4];
#pragma unroll
    for (int i = 0; i < 4; ++i) {
        int c = w * 4 + i;
        st[i] = (c < 8) ? kc[(((size_t)(b * 128 + kb0) * 8) + c) * 64 + lane]
                        : vc[(((size_t)(b * 128 + kb0) * 8) + (c - 8)) * 64 + lane];
    }

    for (int t = 0; t < 32; ++t) {
        __bf16* buf = &lds[t & 1][0];
#pragma unroll
        for (int i = 0; i < 4; ++i)
            *(bf16x8*)(buf + (w * 4 + i) * 512 + lane * 8) = st[i];
        int kbn = kb0 + ((t + 1 < 32) ? t + 1 : t);
#pragma unroll
        for (int i = 0; i < 4; ++i) {
            int c = w * 4 + i;
            st[i] = (c < 8) ? kc[(((size_t)(b * 128 + kbn) * 8) + c) * 64 + lane]
                            : vc[(((size_t)(b * 128 + kbn) * 8) + (c - 8)) * 64 + lane];
        }
        __syncthreads();                  // tile t visible

        bf16x8 akA[4], akB[4];
#pragma unroll
        for (int f = 0; f < 4; ++f) {
            akA[f] = *(const bf16x8*)(buf + (f * 2 + 0) * 512 + lane * 8);
            akB[f] = *(const bf16x8*)(buf + (f * 2 + 1) * 512 + lane * 8);
        }
        bf16x8 pb[2];
#pragma unroll
        for (int s = 0; s < 2; ++s) {
            f32x4 accA = {0.f, 0.f, 0.f, 0.f};
            f32x4 accB = {0.f, 0.f, 0.f, 0.f};
#pragma unroll
            for (int f = 0; f < 4; ++f) {
                accA = __builtin_amdgcn_mfma_f32_16x16x32_bf16(akA[f], bq[s][f], accA, 0, 0, 0);
                accB = __builtin_amdgcn_mfma_f32_16x16x32_bf16(akB[f], bq[s][f], accB, 0, 0, 0);
            }
            bf16x8 p;
            p[0] = (__bf16)__builtin_amdgcn_exp2f(accA[0]);
            p[1] = (__bf16)__builtin_amdgcn_exp2f(accA[1]);
            p[2] = (__bf16)__builtin_amdgcn_exp2f(accA[2]);
            p[3] = (__bf16)__builtin_amdgcn_exp2f(accA[3]);
            p[4] = (__bf16)__builtin_amdgcn_exp2f(accB[0]);
            p[5] = (__bf16)__builtin_amdgcn_exp2f(accB[1]);
            p[6] = (__bf16)__builtin_amdgcn_exp2f(accB[2]);
            p[7] = (__bf16)__builtin_amdgcn_exp2f(accB[3]);
            pb[s] = p;
        }
#pragma unroll
        for (int ds = 0; ds < 8; ++ds) {
            bf16x8 vf = *(const bf16x8*)(buf + (8 + ds) * 512 + lane * 8);
#pragma unroll
            for (int s = 0; s < 2; ++s)
                oacc[s][ds] = __builtin_amdgcn_mfma_f32_16x16x32_bf16(
                    vf, pb[s], oacc[s][ds], 0, 0, 0);
        }
    }

    float* op = part + ((size_t)seg * B_ * N_ + (size_t)b * N_ + q0w) * D_;
#pragma unroll
    for (int s = 0; s < 2; ++s)
#pragma unroll
        for (int ds = 0; ds < 8; ++ds) {
            float4 o4;
            o4.x = oacc[s][ds][0]; o4.y = oacc[s][ds][1];
            o4.z = oacc[s][ds][2]; o4.w = oacc[s][ds][3];
            *(float4*)(op + (size_t)(s * 16 + l15) * D_ + ds * 16 + quad * 4) = o4;
        }
}

// ---------------------------------------------------------------------------
// Kernel E: out = sum of KSEG partials
// ---------------------------------------------------------------------------
__global__ __launch_bounds__(256) void reduce_kernel(
    const float* __restrict__ part, float* __restrict__ out)
{
    int i = blockIdx.x * 256 + threadIdx.x;
    const f32x4* p = (const f32x4*)part;
    f32x4 s = p[i];
#pragma unroll
    for (int sgi = 1; sgi < KSEG; ++sgi) {
        f32x4 t = p[(size_t)sgi * (B_ * N_ * D_ / 4) + i];
        s[0] += t[0]; s[1] += t[1]; s[2] += t[2]; s[3] += t[3];
    }
    ((f32x4*)out)[i] = s;
}

extern "C" void kernel_launch(void* const* d_in, const int* in_sizes, int n_in,
                              void* d_out, int out_size, void* d_ws, size_t ws_size,
                              hipStream_t stream) {
    const float* q = (const float*)d_in[0];
    const float* k = (const float*)d_in[1];
    const float* v = (const float*)d_in[2];
    float* out = (float*)d_out;
    char* ws = (char*)d_ws;
    __bf16* qp = (__bf16*)(ws);
    __bf16* kp = (__bf16*)(ws + OFF_KP);
    __bf16* vp = (__bf16*)(ws + OFF_VP);
    float* l    = (float*)(ws + OFF_L);
    float* part = (float*)(ws + OFF_PART);

    hipLaunchKernelGGL(cvt_kernel, dim3(2560), dim3(256), 0, stream, q, k, v, qp, kp, vp);
    hipMemsetAsync(l, 0, (size_t)B_ * N_ * sizeof(float), stream);
    hipLaunchKernelGGL(stats_kernel, dim3(B_ * 32 * QSEG), dim3(256), 0, stream, qp, kp, l);
    hipLaunchKernelGGL(scalev_kernel, dim3(1024), dim3(256), 0, stream, l, vp);
    hipLaunchKernelGGL(attn_kernel, dim3(B_ * 32 * KSEG), dim3(256), 0, stream, qp, kp, vp, part);
    hipLaunchKernelGGL(reduce_kernel, dim3(B_ * N_ * D_ / 4 / 256), dim3(256), 0, stream, part, out);
}